// Round 3
// baseline (567.620 us; speedup 1.0000x reference)
//
#include <hip/hip_runtime.h>

// nnmodel_35708358099045 R6: I-cache attack — loop the node pipeline.
// Post-mortem R3-R5: 160-180 us invariant across LDS/no-LDS, barriers/none,
// 64/256 TPB; occupancy ~11%, VALUBusy ~27%, HBM ~18% ALL low together.
// The invariant is the ~25 KB fully-unrolled straight-line body (~3100
// instrs, zero reuse) vs 32 KB shared L1I: 8192 waves x 25 KB of one-shot
// instruction fetch at staggered PCs = continuous I$ thrash; issue rate
// 0.24 instr/cy/CU (vs ~2) explains every "all pipes idle" counter.
// Fix: rolling-window loop over the 10 graph nodes (~8 KB hot code, 10x
// reuse): prologue nodes 0-1, k=1..8 {prefetch x/z for k+2, enc_row k+1,
// emit k, store out[k-1]}, tail does the cyclic wrap (s2[9], s2[0]).
// All register arrays compile-time-indexed (named rm/rc/rp rotated by
// unrolled copies — no scratch); runtime k only indexes GLOBAL addresses.
// #pragma unroll 1 pins the loop (default unroll would undo the fix).
// FP order per node identical to R5.

#define HN 10
#define ND 40
#define HF 8
#define TPB 256

__global__ __launch_bounds__(TPB) void gnn_kernel(
    const float* __restrict__ x,          // [B, 40]
    const float* __restrict__ z,          // [B, 10, 8]
    const float* __restrict__ y,          // [B, 40]
    const float* __restrict__ enc_rel_w,  // [8, 1]
    const float* __restrict__ enc_rel_b,  // [8]
    const float* __restrict__ enc_root_w, // [8, 8]
    const float* __restrict__ pred_rel_w, // [8, 8]
    const float* __restrict__ pred_rel_b, // [8]
    const float* __restrict__ pred_root_w,// [8, 8]
    const float* __restrict__ dec_rel_w,  // [1, 8]
    const float* __restrict__ dec_rel_b,  // [1]
    const float* __restrict__ dec_root_w, // [1, 1]
    float* __restrict__ out,              // [B, 40]
    int B)
{
    const long long e = (long long)blockIdx.x * TPB + threadIdx.x;

    const float w = 0.8948393168143698f;  // exp(-(1/3)^2) as fp32

    const float4* xr = (const float4*)(x + e * ND);        // 10 float4
    const float4* zr = (const float4*)(z + e * (HN * HF)); // 20 float4
    const float4* yr = (const float4*)(y + e * ND);        // 10 float4
    float4*       og = (float4*)(out + e * ND);            // 10 float4

    const float drb   = dec_rel_b[0];
    const float droot = dec_root_w[0];

    // encoder GraphConv row: r = relu(agg*erw + erb + z . enc_root_w)
    auto enc_row = [&](float aggv, float4 v0, float4 v1, float (&r)[HF]) {
        float zrow[HF] = {v0.x, v0.y, v0.z, v0.w, v1.x, v1.y, v1.z, v1.w};
        #pragma unroll
        for (int f = 0; f < HF; ++f) {
            float acc = aggv * enc_rel_w[f] + enc_rel_b[f];
            #pragma unroll
            for (int g = 0; g < HF; ++g)
                acc += zrow[g] * enc_root_w[f * HF + g];
            r[f] = fmaxf(acc, 0.0f);
        }
    };

    // predictor + decoder row-dot for center rc with neighbors rm, rp
    auto emit = [&](const float (&rm)[HF], const float (&rc)[HF],
                    const float (&rp)[HF]) -> float {
        float a2[HF];
        #pragma unroll
        for (int f = 0; f < HF; ++f)
            a2[f] = rc[f] + w * (rm[f] + rp[f]);
        float s = 0.0f;
        #pragma unroll
        for (int f = 0; f < HF; ++f) {
            float acc = pred_rel_b[f];
            #pragma unroll
            for (int g = 0; g < HF; ++g)
                acc += a2[g] * pred_rel_w[f * HF + g];
            #pragma unroll
            for (int g = 0; g < HF; ++g)
                acc += rc[g] * pred_root_w[f * HF + g];
            s += fmaxf(acc, 0.0f) * dec_rel_w[f];
        }
        return s;
    };

    auto store_out = [&](int idx, float sa, float sb, float4 yv) {
        const float pair = sa + sb + drb;
        float4 o;
        o.x = (sa + drb) + yv.x * droot;
        o.y = pair       + yv.y * droot;
        o.z = pair       + yv.z * droot;
        o.w = (sb + drb) + yv.w * droot;
        og[idx] = o;
    };

    // ---------------- prologue: nodes 0 and 1 ----------------
    // agg[j] = X[j-1].y+X[j-1].z+X[j-1].w + X[j].x+X[j].y+X[j].z  (cyclic)
    float4 X9 = xr[9];
    float4 Xa = xr[0];
    float4 Xb = xr[1];
    float4 Xc = xr[2];                       // X[k+1] for first body iter (k=1)
    float4 z00 = zr[0], z01 = zr[1];         // node 0
    float4 z10 = zr[2], z11 = zr[3];         // node 1
    float4 zc0 = zr[4], zc1 = zr[5];         // node 2 (consumed body k=1)

    const float agg0 = X9.y + X9.z + X9.w + Xa.x + Xa.y + Xa.z;
    const float agg1 = Xa.y + Xa.z + Xa.w + Xb.x + Xb.y + Xb.z;
    float aggn       = Xb.y + Xb.z + Xb.w + Xc.x + Xc.y + Xc.z;  // agg[2]

    float r0s[HF], r1s[HF];
    enc_row(agg0, z00, z01, r0s);
    enc_row(agg1, z10, z11, r1s);

    float rm[HF], rc[HF];
    #pragma unroll
    for (int f = 0; f < HF; ++f) { rm[f] = r0s[f]; rc[f] = r1s[f]; }

    float s2p = 0.0f, s2_1 = 0.0f;

    // ---------------- rolling-window node loop: k = 1..8 ----------------
    // body: rp = enc_row(node k+1); s2[k] = emit(r[k-1],r[k],r[k+1]);
    //       store out[k-1] (k>=2); prefetch x/z for node k+2.
    #pragma unroll 1
    for (int k = 1; k <= 8; ++k) {
        int kn = k + 2; if (kn > 9) kn -= 10;          // wrap (k=8 -> node 0)
        float4 Xn  = xr[kn];                           // X[k+2]
        float4 zn0 = zr[2 * kn];                       // z node k+2
        float4 zn1 = zr[2 * kn + 1];
        float4 yv  = yr[k - 1];                        // for out[k-1]

        float rp[HF];
        enc_row(aggn, zc0, zc1, rp);                   // node k+1
        float s2c = emit(rm, rc, rp);                  // s2[k]

        if (k == 1) s2_1 = s2c;                        // wave-uniform branch
        if (k >= 2) store_out(k - 1, s2p, s2c, yv);

        // advance window
        aggn = Xc.y + Xc.z + Xc.w + Xn.x + Xn.y + Xn.z;  // agg[k+2]
        Xc = Xn; zc0 = zn0; zc1 = zn1;
        #pragma unroll
        for (int f = 0; f < HF; ++f) { rm[f] = rc[f]; rc[f] = rp[f]; }
        s2p = s2c;
    }

    // ---------------- tail: cyclic wrap (s2[9], s2[0]) ----------------
    // state: rm = r[8], rc = r[9], s2p = s2[8]
    const float s2_9 = emit(rm, rc, r0s);              // emit(r8, r9, r0)
    store_out(8, s2p, s2_9, yr[8]);
    const float s2_0 = emit(rc, r0s, r1s);             // emit(r9, r0, r1)
    store_out(9, s2_9, s2_0, yr[9]);
    store_out(0, s2_0, s2_1, yr[0]);
}

extern "C" void kernel_launch(void* const* d_in, const int* in_sizes, int n_in,
                              void* d_out, int out_size, void* d_ws, size_t ws_size,
                              hipStream_t stream) {
    const float* x          = (const float*)d_in[0];
    const float* z          = (const float*)d_in[1];
    const float* y          = (const float*)d_in[2];
    const float* enc_rel_w  = (const float*)d_in[3];
    const float* enc_rel_b  = (const float*)d_in[4];
    const float* enc_root_w = (const float*)d_in[5];
    const float* pred_rel_w = (const float*)d_in[6];
    const float* pred_rel_b = (const float*)d_in[7];
    const float* pred_root_w= (const float*)d_in[8];
    const float* dec_rel_w  = (const float*)d_in[9];
    const float* dec_rel_b  = (const float*)d_in[10];
    const float* dec_root_w = (const float*)d_in[11];
    float* out = (float*)d_out;

    const int B = in_sizes[0] / ND;       // 524288, divisible by TPB
    const int blocks = B / TPB;
    gnn_kernel<<<blocks, TPB, 0, stream>>>(
        x, z, y, enc_rel_w, enc_rel_b, enc_root_w,
        pred_rel_w, pred_rel_b, pred_root_w,
        dec_rel_w, dec_rel_b, dec_root_w, out, B);
}

// Round 4
// 398.106 us; speedup vs baseline: 1.4258x; 1.4258x over previous
//
#include <hip/hip_runtime.h>

// nnmodel_35708358099045 R7: small loop + line-granular memory access.
// Post-mortem R6: loop fixed occupancy (41%) and code size but FETCH went
// 164->912 MB: per-iter 16-32 B touches of 64 B lines, revisited after the
// line was evicted (32 waves x >1MB/CU between touches) -> HBM re-fetch;
// 16 B/iter partial-line stores -> 1.8x write amp. Fix: make every line's
// consumption atomic-in-time:
//  - x: 10 float4 back-to-back in prologue (hot-line consumption), reduced
//    to agg[0..9] held in a named-reg shift queue (2/iter, no runtime idx).
//  - z: 2 nodes per iteration = exactly one 64 B line per lane per iter,
//    loaded and fully consumed in the same iteration. 4 iterations.
//  - y/out: s2 in a named shift queue; straight-line epilogue does 10 y
//    loads + 10 full-line stores back-to-back.
// #pragma unroll 1 pins the loop. FP order per node identical to R5/R6.

#define HN 10
#define ND 40
#define HF 8
#define TPB 256

__global__ __launch_bounds__(TPB) void gnn_kernel(
    const float* __restrict__ x,          // [B, 40]
    const float* __restrict__ z,          // [B, 10, 8]
    const float* __restrict__ y,          // [B, 40]
    const float* __restrict__ enc_rel_w,  // [8, 1]
    const float* __restrict__ enc_rel_b,  // [8]
    const float* __restrict__ enc_root_w, // [8, 8]
    const float* __restrict__ pred_rel_w, // [8, 8]
    const float* __restrict__ pred_rel_b, // [8]
    const float* __restrict__ pred_root_w,// [8, 8]
    const float* __restrict__ dec_rel_w,  // [1, 8]
    const float* __restrict__ dec_rel_b,  // [1]
    const float* __restrict__ dec_root_w, // [1, 1]
    float* __restrict__ out,              // [B, 40]
    int B)
{
    const long long e = (long long)blockIdx.x * TPB + threadIdx.x;

    const float w = 0.8948393168143698f;  // exp(-(1/3)^2) as fp32

    const float4* xr = (const float4*)(x + e * ND);        // 10 float4
    const float4* zr = (const float4*)(z + e * (HN * HF)); // 20 float4
    const float4* yr = (const float4*)(y + e * ND);        // 10 float4
    float4*       og = (float4*)(out + e * ND);            // 10 float4

    const float drb   = dec_rel_b[0];
    const float droot = dec_root_w[0];

    // encoder GraphConv row: r = relu(agg*erw + erb + z . enc_root_w)
    auto enc_row = [&](float aggv, float4 v0, float4 v1, float (&r)[HF]) {
        float zrow[HF] = {v0.x, v0.y, v0.z, v0.w, v1.x, v1.y, v1.z, v1.w};
        #pragma unroll
        for (int f = 0; f < HF; ++f) {
            float acc = aggv * enc_rel_w[f] + enc_rel_b[f];
            #pragma unroll
            for (int g = 0; g < HF; ++g)
                acc += zrow[g] * enc_root_w[f * HF + g];
            r[f] = fmaxf(acc, 0.0f);
        }
    };

    // predictor + decoder row-dot for center rc with neighbors rm, rp
    auto emit = [&](const float (&rm)[HF], const float (&rc)[HF],
                    const float (&rp)[HF]) -> float {
        float a2[HF];
        #pragma unroll
        for (int f = 0; f < HF; ++f)
            a2[f] = rc[f] + w * (rm[f] + rp[f]);
        float s = 0.0f;
        #pragma unroll
        for (int f = 0; f < HF; ++f) {
            float acc = pred_rel_b[f];
            #pragma unroll
            for (int g = 0; g < HF; ++g)
                acc += a2[g] * pred_rel_w[f * HF + g];
            #pragma unroll
            for (int g = 0; g < HF; ++g)
                acc += rc[g] * pred_root_w[f * HF + g];
            s += fmaxf(acc, 0.0f) * dec_rel_w[f];
        }
        return s;
    };

    auto store_out = [&](int idx, float sa, float sb, float4 yv) {
        const float pair = sa + sb + drb;
        float4 o;
        o.x = (sa + drb) + yv.x * droot;
        o.y = pair       + yv.y * droot;
        o.z = pair       + yv.z * droot;
        o.w = (sb + drb) + yv.w * droot;
        og[idx] = o;
    };

    // -------- prologue: x fully (hot lines), aggs, nodes 0-1 --------
    float4 X0 = xr[0], X1 = xr[1], X2 = xr[2], X3 = xr[3], X4 = xr[4],
           X5 = xr[5], X6 = xr[6], X7 = xr[7], X8 = xr[8], X9 = xr[9];
    // agg[j] = X[j-1].y+.z+.w + X[j].x+.y+.z (cyclic), FP order as R5/R6
    const float a0 = X9.y + X9.z + X9.w + X0.x + X0.y + X0.z;
    const float a1 = X0.y + X0.z + X0.w + X1.x + X1.y + X1.z;
    const float a2v= X1.y + X1.z + X1.w + X2.x + X2.y + X2.z;
    const float a3 = X2.y + X2.z + X2.w + X3.x + X3.y + X3.z;
    const float a4 = X3.y + X3.z + X3.w + X4.x + X4.y + X4.z;
    const float a5 = X4.y + X4.z + X4.w + X5.x + X5.y + X5.z;
    const float a6 = X5.y + X5.z + X5.w + X6.x + X6.y + X6.z;
    const float a7 = X6.y + X6.z + X6.w + X7.x + X7.y + X7.z;
    const float a8 = X7.y + X7.z + X7.w + X8.x + X8.y + X8.z;
    const float a9 = X8.y + X8.z + X8.w + X9.x + X9.y + X9.z;

    // agg queue for loop (nodes 2..9), shifted by 2 per iteration
    float u0 = a2v, u1 = a3, u2 = a4, u3 = a5,
          u4 = a6,  u5 = a7, u6 = a8, u7 = a9;

    // z line 0 (nodes 0,1): one 64 B line, consumed immediately
    {
    }
    float r0s[HF], r1s[HF];
    {
        float4 zq0 = zr[0], zq1 = zr[1], zq2 = zr[2], zq3 = zr[3];
        enc_row(a0, zq0, zq1, r0s);
        enc_row(a1, zq2, zq3, r1s);
    }

    float rm[HF], rc[HF];
    #pragma unroll
    for (int f = 0; f < HF; ++f) { rm[f] = r0s[f]; rc[f] = r1s[f]; }

    // s2[1..8] shift queue
    float t0 = 0.f, t1 = 0.f, t2 = 0.f, t3 = 0.f,
          t4 = 0.f, t5 = 0.f, t6 = 0.f, t7 = 0.f;

    // -------- loop: j=1..4, nodes (2j, 2j+1), one z line per iter --------
    #pragma unroll 1
    for (int j = 1; j <= 4; ++j) {
        float4 q0 = zr[4*j + 0], q1 = zr[4*j + 1],
               q2 = zr[4*j + 2], q3 = zr[4*j + 3];   // exactly one 64B line

        float rp0[HF], rp1[HF];
        enc_row(u0, q0, q1, rp0);                    // node 2j
        enc_row(u1, q2, q3, rp1);                    // node 2j+1

        const float sA = emit(rm, rc, rp0);          // s2[2j-1]
        const float sB = emit(rc, rp0, rp1);         // s2[2j]

        // shift queues (all compile-time names -> pure v_mov, no scratch)
        t0 = t2; t1 = t3; t2 = t4; t3 = t5; t4 = t6; t5 = t7;
        t6 = sA; t7 = sB;
        u0 = u2; u1 = u3; u2 = u4; u3 = u5; u4 = u6; u5 = u7;
        #pragma unroll
        for (int f = 0; f < HF; ++f) { rm[f] = rp0[f]; rc[f] = rp1[f]; }
    }
    // after loop: rm=r[8], rc=r[9]; t0..t7 = s2[1..8]

    // -------- epilogue: y early (overlaps tail emits), wrap emits --------
    float4 Y0 = yr[0], Y1 = yr[1], Y2 = yr[2], Y3 = yr[3], Y4 = yr[4],
           Y5 = yr[5], Y6 = yr[6], Y7 = yr[7], Y8 = yr[8], Y9 = yr[9];

    const float s9 = emit(rm, rc, r0s);              // s2[9] = emit(r8,r9,r0)
    const float s0 = emit(rc, r0s, r1s);             // s2[0] = emit(r9,r0,r1)

    // straight-line full-row store: 10 full float4, back-to-back
    store_out(0, s0, t0, Y0);
    store_out(1, t0, t1, Y1);
    store_out(2, t1, t2, Y2);
    store_out(3, t2, t3, Y3);
    store_out(4, t3, t4, Y4);
    store_out(5, t4, t5, Y5);
    store_out(6, t5, t6, Y6);
    store_out(7, t6, t7, Y7);
    store_out(8, t7, s9, Y8);
    store_out(9, s9, s0, Y9);
}

extern "C" void kernel_launch(void* const* d_in, const int* in_sizes, int n_in,
                              void* d_out, int out_size, void* d_ws, size_t ws_size,
                              hipStream_t stream) {
    const float* x          = (const float*)d_in[0];
    const float* z          = (const float*)d_in[1];
    const float* y          = (const float*)d_in[2];
    const float* enc_rel_w  = (const float*)d_in[3];
    const float* enc_rel_b  = (const float*)d_in[4];
    const float* enc_root_w = (const float*)d_in[5];
    const float* pred_rel_w = (const float*)d_in[6];
    const float* pred_rel_b = (const float*)d_in[7];
    const float* pred_root_w= (const float*)d_in[8];
    const float* dec_rel_w  = (const float*)d_in[9];
    const float* dec_rel_b  = (const float*)d_in[10];
    const float* dec_root_w = (const float*)d_in[11];
    float* out = (float*)d_out;

    const int B = in_sizes[0] / ND;       // 524288, divisible by TPB
    const int blocks = B / TPB;
    gnn_kernel<<<blocks, TPB, 0, stream>>>(
        x, z, y, enc_rel_w, enc_rel_b, enc_root_w,
        pred_rel_w, pred_rel_b, pred_root_w,
        dec_rel_w, dec_rel_b, dec_root_w, out, B);
}